// Round 1
// baseline (1029.787 us; speedup 1.0000x reference)
//
#include <hip/hip_runtime.h>

#define T_DIM 7
#define H_DIM 96
#define W_DIM 96
#define C_DIM 64
#define HW    (H_DIM*W_DIM)          // 9216
#define L_DIM (T_DIM*HW)             // 64512
#define NTAPS 27

// ---------------------------------------------------------------------------
// prep_weights: [O][C][27] -> [27][C][64] (O zero-padded to 64 for offset convs)
// dst holds 4 tensors back-to-back: woff0_t, w0_t, woff1_t, w1_t (110592 floats each)
// ---------------------------------------------------------------------------
__global__ void prep_weights(const float* __restrict__ woff0,
                             const float* __restrict__ w0,
                             const float* __restrict__ woff1,
                             const float* __restrict__ w1,
                             float* __restrict__ dst)
{
    int idx = blockIdx.x * 256 + threadIdx.x;
    const int per = NTAPS * 64 * 64;           // 110592
    if (idx >= 4 * per) return;
    int which = idx / per;
    int r     = idx % per;
    int tap   = r / 4096;
    int c     = (r >> 6) & 63;
    int o     = r & 63;
    const float* src = (which == 0) ? woff0 : (which == 1) ? w0
                     : (which == 2) ? woff1 : w1;
    int omax = (which == 0 || which == 2) ? 54 : 64;
    float v = 0.f;
    if (o < omax) v = src[(o * 64 + c) * NTAPS + tap];
    dst[idx] = v;
}

// ---------------------------------------------------------------------------
// transpose_x: x [C=64][L=64512] -> xt [L][64]  (channels-last)
// ---------------------------------------------------------------------------
__global__ void transpose_x(const float* __restrict__ x, float* __restrict__ xt)
{
    __shared__ float tile[64][65];
    const int tid = threadIdx.x;
    const int lb  = blockIdx.x * 64;
    const int ln  = tid & 63;
    const int q   = tid >> 6;    // 0..3
#pragma unroll
    for (int i = 0; i < 16; ++i) {
        int c = q + 4 * i;
        tile[ln][c] = x[c * L_DIM + lb + ln];
    }
    __syncthreads();
#pragma unroll
    for (int i = 0; i < 16; ++i) {
        int ll = q + 4 * i;
        xt[(lb + ll) * 64 + ln] = tile[ll][ln];
    }
}

// ---------------------------------------------------------------------------
// dcn_kernel: one 128-location tile per block, 27 taps.
//   DEFORM=false : plain 3x3x3 conv sampling (integer shift, zero pad) -> offset conv
//   DEFORM=true  : bilinear sampling with per-(loc,tap) offsets
//   EPI: 0 = +bias, write [loc][64] (offset output)
//        1 = +bias, leakyReLU(0.1), write [loc][64]
//        2 = +bias, +residual (NCDHW), write NCDHW to d_out
// ---------------------------------------------------------------------------
template<bool DEFORM, int EPI>
__global__ __launch_bounds__(256, 2)
void dcn_kernel(const float* __restrict__ xin,   // [L][64]
                const float* __restrict__ off,   // [L][64] (only if DEFORM)
                const float* __restrict__ Wt,    // [27][64][64] = [tap][c][o]
                const float* __restrict__ bias,  // [nbias]
                int nbias,
                const float* __restrict__ resid, // x, NCDHW (EPI==2)
                float* __restrict__ out)
{
    __shared__ float s_lds[128][68];
    __shared__ float w_lds[64][64];
    __shared__ float p_wt[128][4];
    __shared__ int   p_base[128][4];

    const int tid  = threadIdx.x;
    const int t    = blockIdx.x / (HW / 128);
    const int tile = blockIdx.x % (HW / 128);
    const int pos0 = tile * 128;
    const int loc_base = t * HW + pos0;

    // matmul mapping: 4 locations x 8 output channels per thread
    const int lgrp = tid >> 3;         // 0..31
    const int ob   = (tid & 7) * 8;    // 0,8,...,56

    float acc[4][8];
#pragma unroll
    for (int i = 0; i < 4; ++i)
#pragma unroll
        for (int j = 0; j < 8; ++j) acc[i][j] = 0.f;

    const int cg = tid & 63;   // gather channel
    const int gq = tid >> 6;   // 0..3

    for (int k = 0; k < NTAPS; ++k) {
        const int kt = k / 9;
        const int kh = (k % 9) / 3;
        const int kw = k % 3;

        __syncthreads();   // previous tap's matmul finished; safe to overwrite LDS

        // stage this tap's weights: 4096 floats = 1024 float4
        {
            const float4* src = (const float4*)(Wt + k * 4096);
            float4* dstp = (float4*)&w_lds[0][0];
#pragma unroll
            for (int i = 0; i < 4; ++i) dstp[tid + i * 256] = src[tid + i * 256];
        }

        // per-location sampling params
        if (tid < 128) {
            int pos = pos0 + tid;
            int h = pos / W_DIM, w = pos % W_DIM;
            int tp = t + kt - 1;
            bool tv = (tp >= 0) && (tp < T_DIM);
            int tb = (tv ? tp : 0) * HW;
            if (DEFORM) {
                float oh = off[(loc_base + tid) * 64 + 2 * k];
                float ow = off[(loc_base + tid) * 64 + 2 * k + 1];
                float ph = (float)(h + kh - 1) + oh;
                float pw = (float)(w + kw - 1) + ow;
                float h0f = floorf(ph), w0f = floorf(pw);
                float lh = ph - h0f, lw = pw - w0f;
                int h0 = (int)h0f, w0 = (int)w0f;
#pragma unroll
                for (int j = 0; j < 4; ++j) {
                    int hj = h0 + (j >> 1), wj = w0 + (j & 1);
                    bool v = tv && (hj >= 0) && (hj < H_DIM) && (wj >= 0) && (wj < W_DIM);
                    float wh = (j >> 1) ? lh : (1.f - lh);
                    float wwt = (j & 1) ? lw : (1.f - lw);
                    int hc = min(max(hj, 0), H_DIM - 1);
                    int wc = min(max(wj, 0), W_DIM - 1);
                    p_wt[tid][j]   = v ? (wh * wwt) : 0.f;
                    p_base[tid][j] = (tb + hc * W_DIM + wc) * 64;
                }
            } else {
                int hj = h + kh - 1, wj = w + kw - 1;
                bool v = tv && (hj >= 0) && (hj < H_DIM) && (wj >= 0) && (wj < W_DIM);
                int hc = min(max(hj, 0), H_DIM - 1);
                int wc = min(max(wj, 0), W_DIM - 1);
                p_wt[tid][0]   = v ? 1.f : 0.f;
                p_base[tid][0] = (tb + hc * W_DIM + wc) * 64;
            }
        }
        __syncthreads();

        // gather + lerp into s_lds[128][64]
#pragma unroll
        for (int i = 0; i < 32; ++i) {
            int l = gq * 32 + i;
            float v;
            if (DEFORM) {
                v = p_wt[l][0] * xin[p_base[l][0] + cg]
                  + p_wt[l][1] * xin[p_base[l][1] + cg]
                  + p_wt[l][2] * xin[p_base[l][2] + cg]
                  + p_wt[l][3] * xin[p_base[l][3] + cg];
            } else {
                v = p_wt[l][0] * xin[p_base[l][0] + cg];
            }
            s_lds[l][cg] = v;
        }
        __syncthreads();

        // matmul: acc[i][j] += s[lgrp+32i][c] * w[c][ob+j]
#pragma unroll
        for (int c4 = 0; c4 < 16; ++c4) {
            float4 sv[4];
#pragma unroll
            for (int i = 0; i < 4; ++i)
                sv[i] = *(const float4*)&s_lds[lgrp + 32 * i][c4 * 4];
#pragma unroll
            for (int cc = 0; cc < 4; ++cc) {
                const float4 wa = *(const float4*)&w_lds[c4 * 4 + cc][ob];
                const float4 wb = *(const float4*)&w_lds[c4 * 4 + cc][ob + 4];
#pragma unroll
                for (int i = 0; i < 4; ++i) {
                    float s = (cc == 0) ? sv[i].x : (cc == 1) ? sv[i].y
                            : (cc == 2) ? sv[i].z : sv[i].w;
                    acc[i][0] += s * wa.x; acc[i][1] += s * wa.y;
                    acc[i][2] += s * wa.z; acc[i][3] += s * wa.w;
                    acc[i][4] += s * wb.x; acc[i][5] += s * wb.y;
                    acc[i][6] += s * wb.z; acc[i][7] += s * wb.w;
                }
            }
        }
    }

    // epilogue
#pragma unroll
    for (int i = 0; i < 4; ++i) {
        int l   = lgrp + 32 * i;
        int loc = loc_base + l;
        if (EPI == 2) {
#pragma unroll
            for (int j = 0; j < 8; ++j) {
                int o = ob + j;
                float v = acc[i][j] + ((o < nbias) ? bias[o] : 0.f);
                out[o * L_DIM + loc] = v + resid[o * L_DIM + loc];
            }
        } else {
            float vv[8];
#pragma unroll
            for (int j = 0; j < 8; ++j) {
                int o = ob + j;
                float v = acc[i][j] + ((o < nbias) ? bias[o] : 0.f);
                if (EPI == 1) v = (v > 0.f) ? v : 0.1f * v;
                vv[j] = v;
            }
            *(float4*)&out[loc * 64 + ob]     = make_float4(vv[0], vv[1], vv[2], vv[3]);
            *(float4*)&out[loc * 64 + ob + 4] = make_float4(vv[4], vv[5], vv[6], vv[7]);
        }
    }
}

// ---------------------------------------------------------------------------
extern "C" void kernel_launch(void* const* d_in, const int* in_sizes, int n_in,
                              void* d_out, int out_size, void* d_ws, size_t ws_size,
                              hipStream_t stream)
{
    const float* x     = (const float*)d_in[0];
    const float* woff0 = (const float*)d_in[1];
    const float* boff0 = (const float*)d_in[2];
    const float* w0    = (const float*)d_in[3];
    const float* b0    = (const float*)d_in[4];
    const float* woff1 = (const float*)d_in[5];
    const float* boff1 = (const float*)d_in[6];
    const float* w1    = (const float*)d_in[7];
    const float* b1    = (const float*)d_in[8];
    float* out = (float*)d_out;

    float* ws   = (float*)d_ws;
    const int WSZ = NTAPS * 64 * 64;      // 110592
    float* Wt   = ws;                     // 4 * WSZ
    float* xt   = Wt + 4 * WSZ;           // L*64
    float* offb = xt + L_DIM * 64;        // L*64
    float* y    = offb + L_DIM * 64;      // L*64

    prep_weights<<<(4 * WSZ + 255) / 256, 256, 0, stream>>>(woff0, w0, woff1, w1, Wt);
    transpose_x<<<L_DIM / 64, 256, 0, stream>>>(x, xt);

    const int grid = T_DIM * (HW / 128);  // 504

    // layer 0
    dcn_kernel<false, 0><<<grid, 256, 0, stream>>>(xt, nullptr, Wt,           boff0, 54, nullptr, offb);
    dcn_kernel<true,  1><<<grid, 256, 0, stream>>>(xt, offb,    Wt + WSZ,     b0,    64, nullptr, y);
    // layer 1
    dcn_kernel<false, 0><<<grid, 256, 0, stream>>>(y,  nullptr, Wt + 2 * WSZ, boff1, 54, nullptr, offb);
    dcn_kernel<true,  2><<<grid, 256, 0, stream>>>(y,  offb,    Wt + 3 * WSZ, b1,    64, x, out);
}

// Round 2
// 452.260 us; speedup vs baseline: 2.2770x; 2.2770x over previous
//
#include <hip/hip_runtime.h>
#include <hip/hip_bf16.h>

#define T_DIM 7
#define H_DIM 96
#define W_DIM 96
#define HW    (H_DIM*W_DIM)          // 9216
#define L_DIM (T_DIM*HW)             // 64512
#define NTAPS 27

typedef __attribute__((ext_vector_type(8))) short bf16x8;
typedef __attribute__((ext_vector_type(4))) float f32x4;

// LDS swizzle: rotate 16B slot within a 128B row by (row&7). Keeps 16B chunks
// intact (frag reads are b128) and spreads same-column reads across banks.
__device__ __forceinline__ int swz(int row, int colbyte) {
    return row * 128 + (((((colbyte) >> 4) + row) & 7) << 4) + (colbyte & 15);
}

__device__ __forceinline__ unsigned pack_bf16x2(float lo, float hi) {
    __hip_bfloat162 h2 = __float22bfloat162_rn(make_float2(lo, hi));
    return *reinterpret_cast<unsigned*>(&h2);
}

// ---------------------------------------------------------------------------
// prep_weights: [O][C][27] fp32 -> [27][O(64-padded)][C] bf16, 4 tensors.
// ---------------------------------------------------------------------------
__global__ void prep_weights(const float* __restrict__ woff0,
                             const float* __restrict__ w0,
                             const float* __restrict__ woff1,
                             const float* __restrict__ w1,
                             unsigned short* __restrict__ dst)
{
    int idx = blockIdx.x * 256 + threadIdx.x;
    const int per = NTAPS * 64 * 64;           // 110592
    if (idx >= 4 * per) return;
    int which = idx / per;
    int r     = idx % per;
    int tap   = r / 4096;
    int o     = (r >> 6) & 63;
    int c     = r & 63;
    const float* src = (which == 0) ? woff0 : (which == 1) ? w0
                     : (which == 2) ? woff1 : w1;
    int omax = (which == 0 || which == 2) ? 54 : 64;
    float v = 0.f;
    if (o < omax) v = src[(o * 64 + c) * NTAPS + tap];
    __hip_bfloat16 h = __float2bfloat16(v);
    dst[idx] = *reinterpret_cast<unsigned short*>(&h);
}

// ---------------------------------------------------------------------------
// transpose_x: x [C=64][L] -> xt [L][64]  (channels-last fp32)
// ---------------------------------------------------------------------------
__global__ void transpose_x(const float* __restrict__ x, float* __restrict__ xt)
{
    __shared__ float tile[64][65];
    const int tid = threadIdx.x;
    const int lb  = blockIdx.x * 64;
    const int ln  = tid & 63;
    const int q   = tid >> 6;    // 0..3
#pragma unroll
    for (int i = 0; i < 16; ++i) {
        int c = q + 4 * i;
        tile[ln][c] = x[c * L_DIM + lb + ln];
    }
    __syncthreads();
#pragma unroll
    for (int i = 0; i < 16; ++i) {
        int ll = q + 4 * i;
        xt[(lb + ll) * 64 + ln] = tile[ll][ln];
    }
}

// ---------------------------------------------------------------------------
// dcn_mfma: 128-location tile per block, 27 taps, MFMA matmul.
//   DEFORM=false : integer-shift sampling (offset conv)
//   DEFORM=true  : 4-corner bilinear with per-(loc,tap) offsets
//   EPI: 0 = +bias -> [loc][64]; 1 = +bias, leaky -> [loc][64];
//        2 = +bias, +residual -> NCDHW d_out
// ---------------------------------------------------------------------------
template<bool DEFORM, int EPI>
__global__ __launch_bounds__(256, 3)
void dcn_mfma(const float* __restrict__ xin,          // [L][64] fp32
              const float* __restrict__ off,          // [L][64] fp32
              const unsigned short* __restrict__ Wt,  // [27][64][64] bf16 [tap][o][c]
              const float* __restrict__ bias, int nbias,
              const float* __restrict__ resid,        // NCDHW (EPI==2)
              float* __restrict__ out)
{
    __shared__ __align__(16) unsigned char smem[28672];
    unsigned char* s_s = smem;                    // 16KB sampled tile [128][64] bf16 swz
    unsigned char* s_w = smem + 16384;            // 8KB weights [64][64] bf16 swz
    float* p_wt   = (float*)(smem + 24576);       // [128][4]
    int*   p_base = (int*)  (smem + 26624);       // [128][4]

    const int tid  = threadIdx.x;
    const int t    = blockIdx.x / (HW / 128);
    const int tile = blockIdx.x % (HW / 128);
    const int pos0 = tile * 128;
    const int loc_base = t * HW + pos0;

    const int lane = tid & 63;
    const int wave = tid >> 6;
    const int lr   = lane & 15;
    const int lk   = lane >> 4;

    f32x4 acc[2][4];
#pragma unroll
    for (int m = 0; m < 2; ++m)
#pragma unroll
        for (int n = 0; n < 4; ++n) acc[m][n] = (f32x4){0.f, 0.f, 0.f, 0.f};

    const int cq   = tid & 15;   // channel-quarter for gather
    const int lsub = tid >> 4;   // 0..15

    for (int k = 0; k < NTAPS; ++k) {
        const int kt = k / 9;
        const int kh = (k % 9) / 3;
        const int kw = k % 3;

        __syncthreads();   // prev tap fully consumed LDS

        // issue weight loads early (consumed after next barrier)
        const float4* wsrc = (const float4*)(Wt + k * 4096);
        float4 wr0 = wsrc[tid];
        float4 wr1 = wsrc[tid + 256];

        // per-location sampling params
        if (tid < 128) {
            int pos = pos0 + tid;
            int h = pos / W_DIM, w = pos % W_DIM;
            int tp = t + kt - 1;
            bool tv = (tp >= 0) && (tp < T_DIM);
            int tb = (tv ? tp : 0) * HW;
            if (DEFORM) {
                float2 o2 = *(const float2*)(off + (loc_base + tid) * 64 + 2 * k);
                float ph = (float)(h + kh - 1) + o2.x;
                float pw = (float)(w + kw - 1) + o2.y;
                float h0f = floorf(ph), w0f = floorf(pw);
                float lh = ph - h0f, lw = pw - w0f;
                int h0 = (int)h0f, w0 = (int)w0f;
#pragma unroll
                for (int j = 0; j < 4; ++j) {
                    int hj = h0 + (j >> 1), wj = w0 + (j & 1);
                    bool v = tv && (hj >= 0) && (hj < H_DIM) && (wj >= 0) && (wj < W_DIM);
                    float wh = (j >> 1) ? lh : (1.f - lh);
                    float wwt = (j & 1) ? lw : (1.f - lw);
                    int hc = min(max(hj, 0), H_DIM - 1);
                    int wc = min(max(wj, 0), W_DIM - 1);
                    p_wt[tid * 4 + j]   = v ? (wh * wwt) : 0.f;
                    p_base[tid * 4 + j] = (tb + hc * W_DIM + wc) * 64;
                }
            } else {
                int hj = h + kh - 1, wj = w + kw - 1;
                bool v = tv && (hj >= 0) && (hj < H_DIM) && (wj >= 0) && (wj < W_DIM);
                int hc = min(max(hj, 0), H_DIM - 1);
                int wc = min(max(wj, 0), W_DIM - 1);
                p_wt[tid * 4]   = v ? 1.f : 0.f;
                p_base[tid * 4] = (tb + hc * W_DIM + wc) * 64;
            }
        }
        __syncthreads();   // params visible

        // stage weights (prev MFMA done at loop-top barrier)
        {
            int o0 = tid >> 3,          c0 = (tid & 7) << 4;
            int o1 = (tid + 256) >> 3,  c1 = ((tid + 256) & 7) << 4;
            *(float4*)(s_w + swz(o0, c0)) = wr0;
            *(float4*)(s_w + swz(o1, c1)) = wr1;
        }

        // gather + lerp -> s_s (bf16, swizzled)
#pragma unroll
        for (int i = 0; i < 8; ++i) {
            int l = lsub + 16 * i;
            float2 v0 = make_float2(0.f, 0.f);
            float2 v1 = make_float2(0.f, 0.f);
            if (DEFORM) {
                float4 pw = *(const float4*)(p_wt + l * 4);
                int4   pb = *(const int4*)(p_base + l * 4);
                {
                    const float2* s0 = (const float2*)(xin + pb.x);
                    float2 a = s0[cq], b = s0[cq + 16];
                    v0.x += pw.x * a.x; v0.y += pw.x * a.y;
                    v1.x += pw.x * b.x; v1.y += pw.x * b.y;
                }
                {
                    const float2* s0 = (const float2*)(xin + pb.y);
                    float2 a = s0[cq], b = s0[cq + 16];
                    v0.x += pw.y * a.x; v0.y += pw.y * a.y;
                    v1.x += pw.y * b.x; v1.y += pw.y * b.y;
                }
                {
                    const float2* s0 = (const float2*)(xin + pb.z);
                    float2 a = s0[cq], b = s0[cq + 16];
                    v0.x += pw.z * a.x; v0.y += pw.z * a.y;
                    v1.x += pw.z * b.x; v1.y += pw.z * b.y;
                }
                {
                    const float2* s0 = (const float2*)(xin + pb.w);
                    float2 a = s0[cq], b = s0[cq + 16];
                    v0.x += pw.w * a.x; v0.y += pw.w * a.y;
                    v1.x += pw.w * b.x; v1.y += pw.w * b.y;
                }
            } else {
                float wj = p_wt[l * 4];
                int   bj = p_base[l * 4];
                const float2* s0 = (const float2*)(xin + bj);
                float2 a = s0[cq], b = s0[cq + 16];
                v0.x = wj * a.x; v0.y = wj * a.y;
                v1.x = wj * b.x; v1.y = wj * b.y;
            }
            *(unsigned*)(s_s + swz(l, cq * 4))        = pack_bf16x2(v0.x, v0.y);
            *(unsigned*)(s_s + swz(l, (cq + 16) * 4)) = pack_bf16x2(v1.x, v1.y);
        }
        __syncthreads();   // sample tile + weights staged

        // MFMA: acc[m][n] += S[32*wave+16m..][k] * W[k][16n..]
#pragma unroll
        for (int kc = 0; kc < 2; ++kc) {
            const int colb = kc * 64 + lk * 16;
            bf16x8 a0 = *(const bf16x8*)(s_s + swz(wave * 32 + lr,      colb));
            bf16x8 a1 = *(const bf16x8*)(s_s + swz(wave * 32 + 16 + lr, colb));
            bf16x8 b[4];
#pragma unroll
            for (int n = 0; n < 4; ++n)
                b[n] = *(const bf16x8*)(s_w + swz(n * 16 + lr, colb));
#pragma unroll
            for (int n = 0; n < 4; ++n) {
                acc[0][n] = __builtin_amdgcn_mfma_f32_16x16x32_bf16(a0, b[n], acc[0][n], 0, 0, 0);
                acc[1][n] = __builtin_amdgcn_mfma_f32_16x16x32_bf16(a1, b[n], acc[1][n], 0, 0, 0);
            }
        }
    }

    // epilogue: C/D layout col = lane&15, row = (lane>>4)*4 + i
#pragma unroll
    for (int m = 0; m < 2; ++m) {
#pragma unroll
        for (int n = 0; n < 4; ++n) {
            int o = n * 16 + lr;
            float bv = (o < nbias) ? bias[o] : 0.f;
#pragma unroll
            for (int i = 0; i < 4; ++i) {
                int row = wave * 32 + m * 16 + lk * 4 + i;
                int loc = loc_base + row;
                float v = acc[m][n][i] + bv;
                if (EPI == 1) v = (v > 0.f) ? v : 0.1f * v;
                if (EPI == 2) {
                    out[o * L_DIM + loc] = v + resid[o * L_DIM + loc];
                } else {
                    out[loc * 64 + o] = v;
                }
            }
        }
    }
}

// ---------------------------------------------------------------------------
extern "C" void kernel_launch(void* const* d_in, const int* in_sizes, int n_in,
                              void* d_out, int out_size, void* d_ws, size_t ws_size,
                              hipStream_t stream)
{
    const float* x     = (const float*)d_in[0];
    const float* woff0 = (const float*)d_in[1];
    const float* boff0 = (const float*)d_in[2];
    const float* w0    = (const float*)d_in[3];
    const float* b0    = (const float*)d_in[4];
    const float* woff1 = (const float*)d_in[5];
    const float* boff1 = (const float*)d_in[6];
    const float* w1    = (const float*)d_in[7];
    const float* b1    = (const float*)d_in[8];
    float* out = (float*)d_out;

    const int WSZ = NTAPS * 64 * 64;                   // 110592 elems per tensor
    unsigned short* Wt = (unsigned short*)d_ws;        // 4*WSZ bf16
    float* xt   = (float*)d_ws + 221184;               // 884736 B offset
    float* offb = xt + (size_t)L_DIM * 64;
    float* y    = offb + (size_t)L_DIM * 64;

    prep_weights<<<(4 * WSZ + 255) / 256, 256, 0, stream>>>(woff0, w0, woff1, w1, Wt);
    transpose_x<<<L_DIM / 64, 256, 0, stream>>>(x, xt);

    const int grid = T_DIM * (HW / 128);  // 504

    // layer 0
    dcn_mfma<false, 0><<<grid, 256, 0, stream>>>(xt, nullptr, Wt,           boff0, 54, nullptr, offb);
    dcn_mfma<true,  1><<<grid, 256, 0, stream>>>(xt, offb,    Wt + WSZ,     b0,    64, nullptr, y);
    // layer 1
    dcn_mfma<false, 0><<<grid, 256, 0, stream>>>(y,  nullptr, Wt + 2 * WSZ, boff1, 54, nullptr, offb);
    dcn_mfma<true,  2><<<grid, 256, 0, stream>>>(y,  offb,    Wt + 3 * WSZ, b1,    64, x, out);
}